// Round 3
// baseline (3243.090 us; speedup 1.0000x reference)
//
#include <hip/hip_runtime.h>

// 10x [ y = x @ W_in^T + b_in ; LN ; x = y @ W_out^T + b_out ; LN ]
// Mrows=16384, d_in=1024, d_out=4096. Output f32.
// GEMM: 256x256 8-phase template (T1 XCD swizzle + T2 LDS XOR swizzle +
// T3/T4 counted-vmcnt pipeline + T5 setprio), bf16 MFMA 16x16x32.
// R3: LDS-transpose epilogue -> full-line dwordx4 C stores (kills the
// 2x write amplification + write-allocate fetches of the 2B-store epilogue).

typedef __attribute__((ext_vector_type(4))) float f32x4;
typedef __attribute__((ext_vector_type(8))) __bf16 bf16x8;

#define LN_EPS 1e-5f

__device__ __forceinline__ ushort f2bf(float f) {
    union { float f; uint u; } c; c.f = f;
    uint u = c.u;
    uint r = (u + 0x7fffu + ((u >> 16) & 1u)) >> 16;
    return (ushort)r;
}

typedef const __attribute__((address_space(1))) void* gas_ptr;
typedef __attribute__((address_space(3))) void* las_ptr;

__device__ __forceinline__ void gload_lds16(const void* g, void* l) {
    __builtin_amdgcn_global_load_lds((gas_ptr)g, (las_ptr)l, 16, 0, 0);
}

__device__ __forceinline__ bf16x8 ldf(const ushort* base, int byteoff) {
    return *reinterpret_cast<const bf16x8*>(
        reinterpret_cast<const char*>(base) + byteoff);
}

// ---------------------------------------------------------------------------
__global__ __launch_bounds__(256) void conv_f32_bf16(
        const float* __restrict__ in, ushort* __restrict__ outp, int n4) {
    int i = blockIdx.x * 256 + threadIdx.x;
    if (i >= n4) return;
    float4 f = reinterpret_cast<const float4*>(in)[i];
    ushort4 r;
    r.x = f2bf(f.x); r.y = f2bf(f.y); r.z = f2bf(f.z); r.w = f2bf(f.w);
    reinterpret_cast<ushort4*>(outp)[i] = r;
}

// ---------------------------------------------------------------------------
// C[M,N](bf16) = A[M,K](bf16 rm) * B[N,K]^T(bf16, K-contig) + bias[N](f32)
// 256x256 tile, BK=64, 512 thr = 8 waves (2Mx4N), per-wave 128x64 out.
// LDS: lds[buf][mat][half][8192 ushorts] = 128 KiB total.
// Swizzle: within a row (128B = 8 chunks of 16B), chunk p holds logical
// chunk p ^ (row&7); staged via pre-swizzled global source (linear dest).
// ---------------------------------------------------------------------------
template<int M, int N, int K>
__global__ __launch_bounds__(512)
void gemm256_8ph(const ushort* __restrict__ A, const ushort* __restrict__ B,
                 const float* __restrict__ bias, ushort* __restrict__ C) {
    constexpr int NT  = K / 64;
    constexpr int NIT = NT / 2;
    constexpr int NBX = N / 256;
    constexpr int NWG = (M / 256) * NBX;

    __shared__ __attribute__((aligned(16))) ushort lds[2][2][2][8192];

    const int tid  = threadIdx.x;
    const int wid  = tid >> 6;
    const int lane = tid & 63;
    const int wr   = wid >> 2;          // 0..1
    const int wc   = wid & 3;           // 0..3

    int bid = blockIdx.x;
    bid = (bid & 7) * (NWG >> 3) + (bid >> 3);   // XCD swizzle (NWG%8==0)
    const int bn0 = (bid % NBX) * 256;
    const int bm0 = (bid / NBX) * 256;

    // staging: thread -> (row = h*128 + r*64 + trow, src chunk cg)
    const int trow = tid >> 3;                    // 0..63
    const int cg   = (tid & 7) ^ (trow & 7);      // inverse swizzle on source
    const ushort* Asrc = A + (size_t)(bm0 + trow) * K + cg * 8;
    const ushort* Bsrc = B + (size_t)(bn0 + trow) * K + cg * 8;

    // fragment reads: row = ..+fr, k = ks*32 + fq*8 -> chunk ks*4+fq
    const int fr  = lane & 15;
    const int fq  = lane >> 4;
    const int s8  = lane & 7;                     // = row & 7 for all frags
    const int cb0 = ((fq       ^ s8) << 4);
    const int cb1 = (((4 + fq) ^ s8) << 4);
    const int brb = (wc & 1) * 64;                // B row base within half

    const ushort* Ah[2] = { &lds[0][0][wr][0],      &lds[1][0][wr][0] };
    const ushort* Bh[2] = { &lds[0][1][wc >> 1][0], &lds[1][1][wc >> 1][0] };

    f32x4 acc[8][4] = {};
    bf16x8 aLo[4][2], aHi[4][2], bLo[2][2], bHi[2][2];

#define STAGE_A(buf, h, kts) do { \
    gload_lds16(Asrc + (size_t)((h)*128     ) * K + (kts), (void*)&lds[buf][0][h][       wid*512]); \
    gload_lds16(Asrc + (size_t)((h)*128 + 64) * K + (kts), (void*)&lds[buf][0][h][4096 + wid*512]); } while(0)
#define STAGE_B(buf, h, kts) do { \
    gload_lds16(Bsrc + (size_t)((h)*128     ) * K + (kts), (void*)&lds[buf][1][h][       wid*512]); \
    gload_lds16(Bsrc + (size_t)((h)*128 + 64) * K + (kts), (void*)&lds[buf][1][h][4096 + wid*512]); } while(0)

#define READ_ALO(b) do { _Pragma("unroll") for (int i = 0; i < 4; ++i) { \
    aLo[i][0] = ldf(Ah[b], (i*16+fr)*128 + cb0); \
    aLo[i][1] = ldf(Ah[b], (i*16+fr)*128 + cb1); } } while(0)
#define READ_AHI(b) do { _Pragma("unroll") for (int i = 0; i < 4; ++i) { \
    aHi[i][0] = ldf(Ah[b], ((i+4)*16+fr)*128 + cb0); \
    aHi[i][1] = ldf(Ah[b], ((i+4)*16+fr)*128 + cb1); } } while(0)
#define READ_BLO(b) do { _Pragma("unroll") for (int j = 0; j < 2; ++j) { \
    bLo[j][0] = ldf(Bh[b], (brb + j*16 + fr)*128 + cb0); \
    bLo[j][1] = ldf(Bh[b], (brb + j*16 + fr)*128 + cb1); } } while(0)
#define READ_BHI(b) do { _Pragma("unroll") for (int j = 0; j < 2; ++j) { \
    bHi[j][0] = ldf(Bh[b], (brb + (j+2)*16 + fr)*128 + cb0); \
    bHi[j][1] = ldf(Bh[b], (brb + (j+2)*16 + fr)*128 + cb1); } } while(0)

#define MFMA_BLK(AF, ioff, BF, joff) do { \
    _Pragma("unroll") for (int i = 0; i < 4; ++i) \
    _Pragma("unroll") for (int j = 0; j < 2; ++j) { \
        acc[i+ioff][j+joff] = __builtin_amdgcn_mfma_f32_16x16x32_bf16(AF[i][0], BF[j][0], acc[i+ioff][j+joff], 0, 0, 0); \
        acc[i+ioff][j+joff] = __builtin_amdgcn_mfma_f32_16x16x32_bf16(AF[i][1], BF[j][1], acc[i+ioff][j+joff], 0, 0, 0); } } while(0)

#define BARRIER() __builtin_amdgcn_s_barrier()
#define VMCNT4()  asm volatile("s_waitcnt vmcnt(4)" ::: "memory")

    // prologue: tile0 (all 4 halves -> buf0), tile1 B halves -> buf1
    STAGE_B(0, 0, 0);  STAGE_B(0, 1, 0);
    STAGE_A(0, 0, 0);  STAGE_A(0, 1, 0);
    STAGE_B(1, 0, 64); STAGE_B(1, 1, 64);
    VMCNT4();          // tile0's 8 loads drained (4 of tile1-B may fly)
    BARRIER();

    for (int it = 0; it < NIT; ++it) {
        const int k1 = it * 128 + 64;             // tile 2it+1 (-> buf1 A)
        const int k2 = (it * 128 + 128) & (K - 1); // tile 2it+2 (-> buf0)
        const int k3 = (it * 128 + 192) & (K - 1); // tile 2it+3 (-> buf1 B)

        // ph0: Q0 of buf0
        READ_ALO(0); READ_BLO(0);
        STAGE_A(1, 0, k1);
        BARRIER();
        __builtin_amdgcn_s_setprio(1); MFMA_BLK(aLo, 0, bLo, 0); __builtin_amdgcn_s_setprio(0);
        BARRIER();
        // ph1: Q1
        READ_BHI(0);
        STAGE_A(1, 1, k1);
        BARRIER();
        __builtin_amdgcn_s_setprio(1); MFMA_BLK(aLo, 0, bHi, 2); __builtin_amdgcn_s_setprio(0);
        BARRIER();
        // ph2: Q2  (buf0 B region now dead -> restage)
        READ_AHI(0);
        STAGE_B(0, 0, k2);
        BARRIER();
        __builtin_amdgcn_s_setprio(1); MFMA_BLK(aHi, 4, bLo, 0); __builtin_amdgcn_s_setprio(0);
        BARRIER();
        // ph3: Q3
        STAGE_B(0, 1, k2);
        BARRIER();
        __builtin_amdgcn_s_setprio(1); MFMA_BLK(aHi, 4, bHi, 2); __builtin_amdgcn_s_setprio(0);
        VMCNT4();   // tile 2it+1 fully staged (prev ph6/7 + this ph0/1)
        BARRIER();
        // ph4: Q0 of buf1  (buf0 A region dead -> restage)
        READ_ALO(1); READ_BLO(1);
        STAGE_A(0, 0, k2);
        BARRIER();
        __builtin_amdgcn_s_setprio(1); MFMA_BLK(aLo, 0, bLo, 0); __builtin_amdgcn_s_setprio(0);
        BARRIER();
        // ph5: Q1
        READ_BHI(1);
        STAGE_A(0, 1, k2);
        BARRIER();
        __builtin_amdgcn_s_setprio(1); MFMA_BLK(aLo, 0, bHi, 2); __builtin_amdgcn_s_setprio(0);
        BARRIER();
        // ph6: Q2  (buf1 B region dead -> restage for tile 2it+3)
        READ_AHI(1);
        STAGE_B(1, 0, k3);
        BARRIER();
        __builtin_amdgcn_s_setprio(1); MFMA_BLK(aHi, 4, bLo, 0); __builtin_amdgcn_s_setprio(0);
        BARRIER();
        // ph7: Q3
        STAGE_B(1, 1, k3);
        BARRIER();
        __builtin_amdgcn_s_setprio(1); MFMA_BLK(aHi, 4, bHi, 2); __builtin_amdgcn_s_setprio(0);
        VMCNT4();   // tile 2it+2 fully staged (ph2..ph5)
        BARRIER();
    }

    // ---- epilogue: stage C tile in LDS (bf16), store full lines ----
    // Stale prefetches (wrapped k2/k3) still target lds -> must drain first.
    asm volatile("s_waitcnt vmcnt(0)" ::: "memory");
    __syncthreads();

    ushort* eps = (ushort*)&lds[0][0][0][0];      // 256 x 256 ushort = 128 KiB
    #pragma unroll
    for (int j = 0; j < 4; ++j) {
        const int c  = wc * 64 + j * 16 + fr;
        const float bv = bias[bn0 + c];
        #pragma unroll
        for (int i = 0; i < 8; ++i) {
            #pragma unroll
            for (int q = 0; q < 4; ++q) {
                const int rloc = wr * 128 + i * 16 + fq * 4 + q;  // m89 layout
                eps[rloc * 256 + c] = f2bf(acc[i][j][q] + bv);
            }
        }
    }
    __syncthreads();

    // read back row-major, store 16B/lane; 4 lanes/row = 64B-line coverage
    {
        const int rl = tid >> 2;          // 0..127
        const int sc = (tid & 3) * 64;    // col offset (ushorts)
        #pragma unroll
        for (int h = 0; h < 2; ++h) {
            const int r = rl + h * 128;
            const ushort* rp = eps + r * 256 + sc;
            ushort* cp = C + (size_t)(bm0 + r) * N + bn0 + sc;
            #pragma unroll
            for (int k = 0; k < 8; ++k)
                *reinterpret_cast<uint4*>(cp + k * 8) =
                    *reinterpret_cast<const uint4*>(rp + k * 8);
        }
    }
#undef STAGE_A
#undef STAGE_B
#undef READ_ALO
#undef READ_AHI
#undef READ_BLO
#undef READ_BHI
#undef MFMA_BLK
#undef BARRIER
#undef VMCNT4
}

// ---------------------------------------------------------------------------
// Row LayerNorm over last dim W (bf16 in place), one wave per row.
// ---------------------------------------------------------------------------
template<int W, bool F32OUT>
__global__ __launch_bounds__(256)
void ln_rows(ushort* __restrict__ y, float* __restrict__ outp) {
    constexpr int NIT = W / 512;
    const int wid  = threadIdx.x >> 6;
    const int lane = threadIdx.x & 63;
    const size_t row = (size_t)blockIdx.x * 4 + wid;
    ushort* p = y + row * W;

    bf16x8 v[NIT];
    float sum = 0.f, sumsq = 0.f;
    #pragma unroll
    for (int i = 0; i < NIT; ++i) {
        v[i] = *reinterpret_cast<const bf16x8*>(p + i * 512 + lane * 8);
        #pragma unroll
        for (int j = 0; j < 8; ++j) {
            const float f = (float)v[i][j];
            sum += f; sumsq += f * f;
        }
    }
    #pragma unroll
    for (int off = 32; off > 0; off >>= 1) {
        sum   += __shfl_xor(sum, off);
        sumsq += __shfl_xor(sumsq, off);
    }
    const float mean = sum * (1.0f / W);
    const float var  = fmaxf(sumsq * (1.0f / W) - mean * mean, 0.f);
    const float rstd = rsqrtf(var + LN_EPS);

    #pragma unroll
    for (int i = 0; i < NIT; ++i) {
        if constexpr (F32OUT) {
            float* op = outp + row * W + i * 512 + lane * 8;
            float4 o0, o1;
            o0.x = ((float)v[i][0] - mean) * rstd;
            o0.y = ((float)v[i][1] - mean) * rstd;
            o0.z = ((float)v[i][2] - mean) * rstd;
            o0.w = ((float)v[i][3] - mean) * rstd;
            o1.x = ((float)v[i][4] - mean) * rstd;
            o1.y = ((float)v[i][5] - mean) * rstd;
            o1.z = ((float)v[i][6] - mean) * rstd;
            o1.w = ((float)v[i][7] - mean) * rstd;
            reinterpret_cast<float4*>(op)[0] = o0;
            reinterpret_cast<float4*>(op)[1] = o1;
        } else {
            ushort4 r0, r1;
            r0.x = f2bf(((float)v[i][0] - mean) * rstd);
            r0.y = f2bf(((float)v[i][1] - mean) * rstd);
            r0.z = f2bf(((float)v[i][2] - mean) * rstd);
            r0.w = f2bf(((float)v[i][3] - mean) * rstd);
            r1.x = f2bf(((float)v[i][4] - mean) * rstd);
            r1.y = f2bf(((float)v[i][5] - mean) * rstd);
            r1.z = f2bf(((float)v[i][6] - mean) * rstd);
            r1.w = f2bf(((float)v[i][7] - mean) * rstd);
            ushort* op = p + i * 512 + lane * 8;
            reinterpret_cast<ushort4*>(op)[0] = r0;
            reinterpret_cast<ushort4*>(op)[1] = r1;
        }
    }
}

// ---------------------------------------------------------------------------
extern "C" void kernel_launch(void* const* d_in, const int* in_sizes, int n_in,
                              void* d_out, int out_size, void* d_ws, size_t ws_size,
                              hipStream_t stream) {
    const float* x     = (const float*)d_in[0];
    const float* w_in  = (const float*)d_in[1];
    const float* b_in  = (const float*)d_in[2];
    const float* w_out = (const float*)d_in[3];
    const float* b_out = (const float*)d_in[4];

    constexpr int Mrows = 16384;
    constexpr int Din   = 1024;
    constexpr int Dout  = 4096;

    char* ws = (char*)d_ws;
    ushort* wib = (ushort*)ws;  ws += (size_t)Dout * Din * 2;
    ushort* wob = (ushort*)ws;  ws += (size_t)Din * Dout * 2;
    ushort* xb  = (ushort*)ws;  ws += (size_t)Mrows * Din * 2;
    ushort* yb  = (ushort*)ws;

    const dim3 blk(256);

    conv_f32_bf16<<<(Dout * Din / 4) / 256, blk, 0, stream>>>(w_in,  wib, Dout * Din / 4);
    conv_f32_bf16<<<(Din * Dout / 4) / 256, blk, 0, stream>>>(w_out, wob, Din * Dout / 4);
    conv_f32_bf16<<<(Mrows * Din / 4) / 256, blk, 0, stream>>>(x, xb, Mrows * Din / 4);

    for (int it = 0; it < 10; ++it) {
        gemm256_8ph<Mrows, Dout, Din>
            <<<(Mrows / 256) * (Dout / 256), dim3(512), 0, stream>>>(xb, wib, b_in, yb);
        ln_rows<Dout, false><<<Mrows / 4, blk, 0, stream>>>(yb, nullptr);
        gemm256_8ph<Mrows, Din, Dout>
            <<<(Mrows / 256) * (Din / 256), dim3(512), 0, stream>>>(yb, wob, b_out, xb);
        if (it < 9) {
            ln_rows<Din, false><<<Mrows / 4, blk, 0, stream>>>(xb, nullptr);
        } else {
            ln_rows<Din, true><<<Mrows / 4, blk, 0, stream>>>(xb, (float*)d_out);
        }
    }
}

// Round 4
// 2952.326 us; speedup vs baseline: 1.0985x; 1.0985x over previous
//
#include <hip/hip_runtime.h>

// 10x [ y = x @ W_in^T + b_in ; LN ; x = y @ W_out^T + b_out ; LN ]
// Mrows=16384, d_in=1024, d_out=4096. Output f32.
// GEMM: 256x256 8-phase template, bf16 MFMA 16x16x32.
// R4: (a) N-strip XCD swizzle for GEMM1 (NBX=16): each XCD owns 2 N-panels
//     -> B-panel (1MB) stays L2-resident all dispatch, kills ~1GB/dispatch
//     of L3 B-restage traffic that capped the operand feed at ~6 TB/s.
//     (b) epilogue LDS chunk-swizzle (write col ^= ((row>>2)&3)<<4, matched
//     readback lane map) -> conflict-free epilogue, full-line C stores.

typedef __attribute__((ext_vector_type(4))) float f32x4;
typedef __attribute__((ext_vector_type(8))) __bf16 bf16x8;

#define LN_EPS 1e-5f

__device__ __forceinline__ ushort f2bf(float f) {
    union { float f; uint u; } c; c.f = f;
    uint u = c.u;
    uint r = (u + 0x7fffu + ((u >> 16) & 1u)) >> 16;
    return (ushort)r;
}

typedef const __attribute__((address_space(1))) void* gas_ptr;
typedef __attribute__((address_space(3))) void* las_ptr;

__device__ __forceinline__ void gload_lds16(const void* g, void* l) {
    __builtin_amdgcn_global_load_lds((gas_ptr)g, (las_ptr)l, 16, 0, 0);
}

__device__ __forceinline__ bf16x8 ldf(const ushort* base, int byteoff) {
    return *reinterpret_cast<const bf16x8*>(
        reinterpret_cast<const char*>(base) + byteoff);
}

// ---------------------------------------------------------------------------
__global__ __launch_bounds__(256) void conv_f32_bf16(
        const float* __restrict__ in, ushort* __restrict__ outp, int n4) {
    int i = blockIdx.x * 256 + threadIdx.x;
    if (i >= n4) return;
    float4 f = reinterpret_cast<const float4*>(in)[i];
    ushort4 r;
    r.x = f2bf(f.x); r.y = f2bf(f.y); r.z = f2bf(f.z); r.w = f2bf(f.w);
    reinterpret_cast<ushort4*>(outp)[i] = r;
}

// ---------------------------------------------------------------------------
// C[M,N](bf16) = A[M,K](bf16 rm) * B[N,K]^T(bf16, K-contig) + bias[N](f32)
// 256x256 tile, BK=64, 512 thr = 8 waves (2Mx4N), per-wave 128x64 out.
// ---------------------------------------------------------------------------
template<int M, int N, int K>
__global__ __launch_bounds__(512)
void gemm256_8ph(const ushort* __restrict__ A, const ushort* __restrict__ B,
                 const float* __restrict__ bias, ushort* __restrict__ C) {
    constexpr int NT  = K / 64;
    constexpr int NIT = NT / 2;
    constexpr int NBX = N / 256;
    constexpr int NWG = (M / 256) * NBX;

    __shared__ __attribute__((aligned(16))) ushort lds[2][2][2][8192];

    const int tid  = threadIdx.x;
    const int wid  = tid >> 6;
    const int lane = tid & 63;
    const int wr   = wid >> 2;          // 0..1
    const int wc   = wid & 3;           // 0..3

    int bn0, bm0;
    if constexpr (NBX == 16) {
        // N-strip: XCD x (= orig bid % 8) owns N-panels {2x, 2x+1}, all M.
        // Concurrent set per XCD = 16 M-panels x 2 N-panels: B (1MB) L2-
        // resident for whole dispatch; A-slices stream once, shared x2.
        const int x = blockIdx.x & 7, j = blockIdx.x >> 3;
        bn0 = (x * 2 + (j & 1)) * 256;
        bm0 = (j >> 1) * 256;
    } else {
        int bid = (blockIdx.x & 7) * (NWG >> 3) + (blockIdx.x >> 3);
        bn0 = (bid % NBX) * 256;
        bm0 = (bid / NBX) * 256;
    }

    // staging: thread -> (row = h*128 + r*64 + trow, src chunk cg)
    const int trow = tid >> 3;                    // 0..63
    const int cg   = (tid & 7) ^ (trow & 7);      // inverse swizzle on source
    const ushort* Asrc = A + (size_t)(bm0 + trow) * K + cg * 8;
    const ushort* Bsrc = B + (size_t)(bn0 + trow) * K + cg * 8;

    // fragment reads: row = ..+fr, k = ks*32 + fq*8 -> chunk ks*4+fq
    const int fr  = lane & 15;
    const int fq  = lane >> 4;
    const int s8  = lane & 7;                     // = row & 7 for all frags
    const int cb0 = ((fq       ^ s8) << 4);
    const int cb1 = (((4 + fq) ^ s8) << 4);
    const int brb = (wc & 1) * 64;                // B row base within half

    const ushort* Ah[2] = { &lds[0][0][wr][0],      &lds[1][0][wr][0] };
    const ushort* Bh[2] = { &lds[0][1][wc >> 1][0], &lds[1][1][wc >> 1][0] };

    f32x4 acc[8][4] = {};
    bf16x8 aLo[4][2], aHi[4][2], bLo[2][2], bHi[2][2];

#define STAGE_A(buf, h, kts) do { \
    gload_lds16(Asrc + (size_t)((h)*128     ) * K + (kts), (void*)&lds[buf][0][h][       wid*512]); \
    gload_lds16(Asrc + (size_t)((h)*128 + 64) * K + (kts), (void*)&lds[buf][0][h][4096 + wid*512]); } while(0)
#define STAGE_B(buf, h, kts) do { \
    gload_lds16(Bsrc + (size_t)((h)*128     ) * K + (kts), (void*)&lds[buf][1][h][       wid*512]); \
    gload_lds16(Bsrc + (size_t)((h)*128 + 64) * K + (kts), (void*)&lds[buf][1][h][4096 + wid*512]); } while(0)

#define READ_ALO(b) do { _Pragma("unroll") for (int i = 0; i < 4; ++i) { \
    aLo[i][0] = ldf(Ah[b], (i*16+fr)*128 + cb0); \
    aLo[i][1] = ldf(Ah[b], (i*16+fr)*128 + cb1); } } while(0)
#define READ_AHI(b) do { _Pragma("unroll") for (int i = 0; i < 4; ++i) { \
    aHi[i][0] = ldf(Ah[b], ((i+4)*16+fr)*128 + cb0); \
    aHi[i][1] = ldf(Ah[b], ((i+4)*16+fr)*128 + cb1); } } while(0)
#define READ_BLO(b) do { _Pragma("unroll") for (int j = 0; j < 2; ++j) { \
    bLo[j][0] = ldf(Bh[b], (brb + j*16 + fr)*128 + cb0); \
    bLo[j][1] = ldf(Bh[b], (brb + j*16 + fr)*128 + cb1); } } while(0)
#define READ_BHI(b) do { _Pragma("unroll") for (int j = 0; j < 2; ++j) { \
    bHi[j][0] = ldf(Bh[b], (brb + (j+2)*16 + fr)*128 + cb0); \
    bHi[j][1] = ldf(Bh[b], (brb + (j+2)*16 + fr)*128 + cb1); } } while(0)

#define MFMA_BLK(AF, ioff, BF, joff) do { \
    _Pragma("unroll") for (int i = 0; i < 4; ++i) \
    _Pragma("unroll") for (int j = 0; j < 2; ++j) { \
        acc[i+ioff][j+joff] = __builtin_amdgcn_mfma_f32_16x16x32_bf16(AF[i][0], BF[j][0], acc[i+ioff][j+joff], 0, 0, 0); \
        acc[i+ioff][j+joff] = __builtin_amdgcn_mfma_f32_16x16x32_bf16(AF[i][1], BF[j][1], acc[i+ioff][j+joff], 0, 0, 0); } } while(0)

#define BARRIER() __builtin_amdgcn_s_barrier()
#define VMCNT4()  asm volatile("s_waitcnt vmcnt(4)" ::: "memory")

    // prologue: tile0 (all 4 halves -> buf0), tile1 B halves -> buf1
    STAGE_B(0, 0, 0);  STAGE_B(0, 1, 0);
    STAGE_A(0, 0, 0);  STAGE_A(0, 1, 0);
    STAGE_B(1, 0, 64); STAGE_B(1, 1, 64);
    VMCNT4();
    BARRIER();

    for (int it = 0; it < NIT; ++it) {
        const int k1 = it * 128 + 64;              // tile 2it+1 (-> buf1 A)
        const int k2 = (it * 128 + 128) & (K - 1); // tile 2it+2 (-> buf0)
        const int k3 = (it * 128 + 192) & (K - 1); // tile 2it+3 (-> buf1 B)

        // ph0
        READ_ALO(0); READ_BLO(0);
        STAGE_A(1, 0, k1);
        BARRIER();
        __builtin_amdgcn_s_setprio(1); MFMA_BLK(aLo, 0, bLo, 0); __builtin_amdgcn_s_setprio(0);
        BARRIER();
        // ph1
        READ_BHI(0);
        STAGE_A(1, 1, k1);
        BARRIER();
        __builtin_amdgcn_s_setprio(1); MFMA_BLK(aLo, 0, bHi, 2); __builtin_amdgcn_s_setprio(0);
        BARRIER();
        // ph2
        READ_AHI(0);
        STAGE_B(0, 0, k2);
        BARRIER();
        __builtin_amdgcn_s_setprio(1); MFMA_BLK(aHi, 4, bLo, 0); __builtin_amdgcn_s_setprio(0);
        BARRIER();
        // ph3
        STAGE_B(0, 1, k2);
        BARRIER();
        __builtin_amdgcn_s_setprio(1); MFMA_BLK(aHi, 4, bHi, 2); __builtin_amdgcn_s_setprio(0);
        VMCNT4();
        BARRIER();
        // ph4
        READ_ALO(1); READ_BLO(1);
        STAGE_A(0, 0, k2);
        BARRIER();
        __builtin_amdgcn_s_setprio(1); MFMA_BLK(aLo, 0, bLo, 0); __builtin_amdgcn_s_setprio(0);
        BARRIER();
        // ph5
        READ_BHI(1);
        STAGE_A(0, 1, k2);
        BARRIER();
        __builtin_amdgcn_s_setprio(1); MFMA_BLK(aLo, 0, bHi, 2); __builtin_amdgcn_s_setprio(0);
        BARRIER();
        // ph6
        READ_AHI(1);
        STAGE_B(1, 0, k3);
        BARRIER();
        __builtin_amdgcn_s_setprio(1); MFMA_BLK(aHi, 4, bLo, 0); __builtin_amdgcn_s_setprio(0);
        BARRIER();
        // ph7
        STAGE_B(1, 1, k3);
        BARRIER();
        __builtin_amdgcn_s_setprio(1); MFMA_BLK(aHi, 4, bHi, 2); __builtin_amdgcn_s_setprio(0);
        VMCNT4();
        BARRIER();
    }

    // ---- epilogue: stage C tile in LDS (bf16, chunk-swizzled), store lines --
    asm volatile("s_waitcnt vmcnt(0)" ::: "memory");
    __syncthreads();

    // swizzle: ushort col' = col ^ (((row>>2)&3)<<4)  (16B-chunk granule)
    ushort* eps = (ushort*)&lds[0][0][0][0];      // 256 x 256 ushort = 128 KiB
    #pragma unroll
    for (int j = 0; j < 4; ++j) {
        const int c  = wc * 64 + j * 16 + fr;
        const float bv = bias[bn0 + c];
        #pragma unroll
        for (int i = 0; i < 8; ++i) {
            const int rbase = wr * 128 + i * 16;
            #pragma unroll
            for (int q = 0; q < 4; ++q) {
                const int rloc = rbase + fq * 4 + q;          // m89 layout
                const int csw  = c ^ (((rloc >> 2) & 3) << 4);
                eps[rloc * 256 + csw] = f2bf(acc[i][j][q] + bv);
            }
        }
    }
    __syncthreads();

    // readback: thread t -> row rbase = 16*(g>>2) + 4*q4 + (g&3), chunks 4k+a
    // (quarter-wave = 4 rows with distinct (r>>2)&3 -> conflict-free; each
    // lane-quad covers 64B contiguous of one row -> full-line global stores)
    {
        const int g  = tid >> 4;          // 0..31
        const int q4 = (tid >> 2) & 3;
        const int a  = tid & 3;
        const int rb = (g >> 2) * 16 + q4 * 4 + (g & 3);   // 0..127
        const int keyx = q4 << 4;          // ((r>>2)&3)<<4, same for both halves
        #pragma unroll
        for (int h = 0; h < 2; ++h) {
            const int r = rb + h * 128;
            const ushort* rp = eps + r * 256;
            ushort* cp = C + (size_t)(bm0 + r) * N + bn0;
            #pragma unroll
            for (int k = 0; k < 8; ++k) {
                const int col = (4 * k + a) * 8;
                *reinterpret_cast<uint4*>(cp + col) =
                    *reinterpret_cast<const uint4*>(rp + (col ^ keyx));
            }
        }
    }
#undef STAGE_A
#undef STAGE_B
#undef READ_ALO
#undef READ_AHI
#undef READ_BLO
#undef READ_BHI
#undef MFMA_BLK
#undef BARRIER
#undef VMCNT4
}

// ---------------------------------------------------------------------------
// Row LayerNorm over last dim W (bf16 in place), one wave per row.
// ---------------------------------------------------------------------------
template<int W, bool F32OUT>
__global__ __launch_bounds__(256)
void ln_rows(ushort* __restrict__ y, float* __restrict__ outp) {
    constexpr int NIT = W / 512;
    const int wid  = threadIdx.x >> 6;
    const int lane = threadIdx.x & 63;
    const size_t row = (size_t)blockIdx.x * 4 + wid;
    ushort* p = y + row * W;

    bf16x8 v[NIT];
    float sum = 0.f, sumsq = 0.f;
    #pragma unroll
    for (int i = 0; i < NIT; ++i) {
        v[i] = *reinterpret_cast<const bf16x8*>(p + i * 512 + lane * 8);
        #pragma unroll
        for (int j = 0; j < 8; ++j) {
            const float f = (float)v[i][j];
            sum += f; sumsq += f * f;
        }
    }
    #pragma unroll
    for (int off = 32; off > 0; off >>= 1) {
        sum   += __shfl_xor(sum, off);
        sumsq += __shfl_xor(sumsq, off);
    }
    const float mean = sum * (1.0f / W);
    const float var  = fmaxf(sumsq * (1.0f / W) - mean * mean, 0.f);
    const float rstd = rsqrtf(var + LN_EPS);

    #pragma unroll
    for (int i = 0; i < NIT; ++i) {
        if constexpr (F32OUT) {
            float* op = outp + row * W + i * 512 + lane * 8;
            float4 o0, o1;
            o0.x = ((float)v[i][0] - mean) * rstd;
            o0.y = ((float)v[i][1] - mean) * rstd;
            o0.z = ((float)v[i][2] - mean) * rstd;
            o0.w = ((float)v[i][3] - mean) * rstd;
            o1.x = ((float)v[i][4] - mean) * rstd;
            o1.y = ((float)v[i][5] - mean) * rstd;
            o1.z = ((float)v[i][6] - mean) * rstd;
            o1.w = ((float)v[i][7] - mean) * rstd;
            reinterpret_cast<float4*>(op)[0] = o0;
            reinterpret_cast<float4*>(op)[1] = o1;
        } else {
            ushort4 r0, r1;
            r0.x = f2bf(((float)v[i][0] - mean) * rstd);
            r0.y = f2bf(((float)v[i][1] - mean) * rstd);
            r0.z = f2bf(((float)v[i][2] - mean) * rstd);
            r0.w = f2bf(((float)v[i][3] - mean) * rstd);
            r1.x = f2bf(((float)v[i][4] - mean) * rstd);
            r1.y = f2bf(((float)v[i][5] - mean) * rstd);
            r1.z = f2bf(((float)v[i][6] - mean) * rstd);
            r1.w = f2bf(((float)v[i][7] - mean) * rstd);
            ushort* op = p + i * 512 + lane * 8;
            reinterpret_cast<ushort4*>(op)[0] = r0;
            reinterpret_cast<ushort4*>(op)[1] = r1;
        }
    }
}

// ---------------------------------------------------------------------------
extern "C" void kernel_launch(void* const* d_in, const int* in_sizes, int n_in,
                              void* d_out, int out_size, void* d_ws, size_t ws_size,
                              hipStream_t stream) {
    const float* x     = (const float*)d_in[0];
    const float* w_in  = (const float*)d_in[1];
    const float* b_in  = (const float*)d_in[2];
    const float* w_out = (const float*)d_in[3];
    const float* b_out = (const float*)d_in[4];

    constexpr int Mrows = 16384;
    constexpr int Din   = 1024;
    constexpr int Dout  = 4096;

    char* ws = (char*)d_ws;
    ushort* wib = (ushort*)ws;  ws += (size_t)Dout * Din * 2;
    ushort* wob = (ushort*)ws;  ws += (size_t)Din * Dout * 2;
    ushort* xb  = (ushort*)ws;  ws += (size_t)Mrows * Din * 2;
    ushort* yb  = (ushort*)ws;

    const dim3 blk(256);

    conv_f32_bf16<<<(Dout * Din / 4) / 256, blk, 0, stream>>>(w_in,  wib, Dout * Din / 4);
    conv_f32_bf16<<<(Din * Dout / 4) / 256, blk, 0, stream>>>(w_out, wob, Din * Dout / 4);
    conv_f32_bf16<<<(Mrows * Din / 4) / 256, blk, 0, stream>>>(x, xb, Mrows * Din / 4);

    for (int it = 0; it < 10; ++it) {
        gemm256_8ph<Mrows, Dout, Din>
            <<<(Mrows / 256) * (Dout / 256), dim3(512), 0, stream>>>(xb, wib, b_in, yb);
        ln_rows<Dout, false><<<Mrows / 4, blk, 0, stream>>>(yb, nullptr);
        gemm256_8ph<Mrows, Din, Dout>
            <<<(Mrows / 256) * (Din / 256), dim3(512), 0, stream>>>(yb, wob, b_out, xb);
        if (it < 9) {
            ln_rows<Din, false><<<Mrows / 4, blk, 0, stream>>>(xb, nullptr);
        } else {
            ln_rows<Din, true><<<Mrows / 4, blk, 0, stream>>>(xb, (float*)d_out);
        }
    }
}